// Round 3
// baseline (189.919 us; speedup 1.0000x reference)
//
#include <hip/hip_runtime.h>
#include <hip/hip_bf16.h>

#define DD 32
#define HH 32
#define WW 32
#define NN 32768
#define BB 2
#define CF 256
#define CC 21
#define FD 64
#define KK 19
#define BKP 32

// 19 stencil offsets with |dx|+|dy|+|dz| <= 2 (order irrelevant: softmax+sum over k)
__device__ const int OFF[19][3] = {
    {-1,-1, 0}, {-1, 0,-1}, {-1, 0, 0}, {-1, 0, 1}, {-1, 1, 0},
    { 0,-1,-1}, { 0,-1, 0}, { 0,-1, 1}, { 0, 0,-1}, { 0, 0, 0},
    { 0, 0, 1}, { 0, 1,-1}, { 0, 1, 0}, { 0, 1, 1},
    { 1,-1, 0}, { 1, 0,-1}, { 1, 0, 0}, { 1, 0, 1}, { 1, 1, 0}
};

// ---------------- Kernel 1: projection GEMM ----------------
// C[b,n,j] = sum_c f[b,c,n] * Wcat[c,j] + bias[j]; j 0-63 theta, 64-127 phi.
// tile: 64 rows(n) x 128 cols, BK=32, 256 threads, micro 4x(4+4).
// b-fragment cols split (tj*4, 64+tj*4) -> each LDS read is 256B contiguous
// per wave -> zero bank conflicts. 1024 blocks -> 4 blocks/CU.
__global__ __launch_bounds__(256) void proj_kernel(
    const float* __restrict__ f,
    const float* __restrict__ thw, const float* __restrict__ thb,
    const float* __restrict__ phw, const float* __restrict__ phb,
    float* __restrict__ theta, float* __restrict__ phi)
{
    __shared__ __align__(16) float As[BKP][64];    // 8 KB
    __shared__ __align__(16) float Bs[BKP][128];   // 16 KB
    int blk = blockIdx.x;
    int b = blk >> 9;                 // 512 blocks per batch
    int n0 = (blk & 511) * 64;
    int tid = threadIdx.x;
    int tm = tid >> 4;                // 0..15 -> row group m0 = tm*4
    int tj = tid & 15;                // cols tj*4 (theta) and 64+tj*4 (phi)
    int m0 = tm * 4, j0 = tj * 4;

    float acc[4][8];
#pragma unroll
    for (int r = 0; r < 4; ++r)
#pragma unroll
        for (int jj = 0; jj < 8; ++jj) acc[r][jj] = 0.f;

    const float* fb = f + (size_t)b * CF * NN;

    for (int k0 = 0; k0 < CF; k0 += BKP) {
        // stage A: 32x64 floats = 512 float4, 2 per thread
#pragma unroll
        for (int i = 0; i < 2; ++i) {
            int idx = i * 256 + tid;
            int kk = idx >> 4, c4 = (idx & 15) * 4;
            *(float4*)&As[kk][c4] = *(const float4*)(fb + (size_t)(k0 + kk) * NN + n0 + c4);
        }
        // stage B: 32x128 floats = 1024 float4, 4 per thread
#pragma unroll
        for (int i = 0; i < 4; ++i) {
            int idx = i * 256 + tid;
            int kk = idx >> 5, j4 = (idx & 31) * 4;
            float4 wv;
            if (j4 < 64) wv = *(const float4*)(thw + (k0 + kk) * 64 + j4);
            else         wv = *(const float4*)(phw + (k0 + kk) * 64 + (j4 - 64));
            *(float4*)&Bs[kk][j4] = wv;
        }
        __syncthreads();
#pragma unroll
        for (int kk = 0; kk < BKP; ++kk) {
            float4 av = *(float4*)&As[kk][m0];
            float4 b0 = *(float4*)&Bs[kk][j0];
            float4 b1 = *(float4*)&Bs[kk][64 + j0];
            float a[4] = {av.x, av.y, av.z, av.w};
            float bb[8] = {b0.x, b0.y, b0.z, b0.w, b1.x, b1.y, b1.z, b1.w};
#pragma unroll
            for (int r = 0; r < 4; ++r)
#pragma unroll
                for (int jj = 0; jj < 8; ++jj) acc[r][jj] = fmaf(a[r], bb[jj], acc[r][jj]);
        }
        __syncthreads();
    }

    float4 tb = *(const float4*)(thb + j0);
    float4 pb = *(const float4*)(phb + j0);
#pragma unroll
    for (int r = 0; r < 4; ++r) {
        int n = n0 + m0 + r;
        float4 ot = {acc[r][0] + tb.x, acc[r][1] + tb.y, acc[r][2] + tb.z, acc[r][3] + tb.w};
        float4 op = {acc[r][4] + pb.x, acc[r][5] + pb.y, acc[r][6] + pb.z, acc[r][7] + pb.w};
        *(float4*)(theta + ((size_t)b * NN + n) * 64 + j0) = ot;
        *(float4*)(phi   + ((size_t)b * NN + n) * 64 + j0) = op;
    }
}

// ---------------- Kernel 2: geo projection ----------------
__global__ __launch_bounds__(256) void geo_kernel(
    const float* __restrict__ gtw, const float* __restrict__ gtb,
    const float* __restrict__ gpw, const float* __restrict__ gpb,
    float* __restrict__ gth, float* __restrict__ gph)
{
    __shared__ float pe_s[4][48];
    int tid = threadIdx.x;
    int n_base = blockIdx.x * 4;
    if (tid < 192) {
        int node = tid / 48, p = tid % 48;
        int n = n_base + node;
        int d = n >> 10, h = (n >> 5) & 31, w = n & 31;
        int a = p / 16, rem = p % 16, i = rem >> 1, sc = rem & 1;
        float coord = (a == 0) ? (float)d : (a == 1) ? (float)h : (float)w;
        float div = expf(-9.210340371976184f * (float)i * 0.125f);  // (1e-4)^(i/8)
        float ang = coord * div;
        pe_s[node][p] = sc ? cosf(ang) : sinf(ang);
    }
    __syncthreads();
    int node = tid >> 6, j = tid & 63;
    int n = n_base + node;
    float at = gtb[j], ap = gpb[j];
#pragma unroll
    for (int p = 0; p < 48; ++p) {
        float pv = pe_s[node][p];
        at += pv * gtw[p * 64 + j];
        ap += pv * gpw[p * 64 + j];
    }
    gth[(size_t)n * 64 + j] = at;
    gph[(size_t)n * 64 + j] = ap;
}

// ---------------- Kernel 2b: geo scores (batch-independent) ----------------
__global__ __launch_bounds__(256) void geo_score_kernel(
    const float* __restrict__ gth, const float* __restrict__ gph,
    float* __restrict__ gsc)
{
    int wid = blockIdx.x * 4 + (threadIdx.x >> 6);
    int lane = threadIdx.x & 63;
    int node = lane / 19;
    int k = lane - node * 19;
    int n = wid * 3 + node;
    bool active = (node < 3) && (n < NN);
    if (!active) return;

    int d = n >> 10, h = (n >> 5) & 31, w = n & 31;
    int nd = d + OFF[k][0], nh = h + OFF[k][1], nw = w + OFF[k][2];
    bool valid = ((unsigned)nd < 32u) && ((unsigned)nh < 32u) && ((unsigned)nw < 32u);
    int nn = valid ? ((nd << 10) + (nh << 5) + nw) : n;

    const float* tr = gth + (size_t)n * 64;
    const float* pr = gph + (size_t)nn * 64;
    float acc = 0.f;
#pragma unroll
    for (int i = 0; i < 16; ++i) {
        float4 t = *(const float4*)(tr + i * 4);
        float4 p = *(const float4*)(pr + i * 4);
        acc = fmaf(t.x, p.x, acc); acc = fmaf(t.y, p.y, acc);
        acc = fmaf(t.z, p.z, acc); acc = fmaf(t.w, p.w, acc);
    }
    const float rs = 0.2294157338705618f;  // 1/sqrt(19)
    gsc[(size_t)n * KK + k] = valid ? acc * rs : -INFINITY;
}

// ---------------- Kernel 3: scores + masked softmax ----------------
__global__ __launch_bounds__(256) void score_kernel(
    const float* __restrict__ theta, const float* __restrict__ phi,
    const float* __restrict__ gsc, float* __restrict__ wgt)
{
    __shared__ float sbuf[4][3][20];
    __shared__ float ebuf[4][3][20];
    int wv = threadIdx.x >> 6;
    int lane = threadIdx.x & 63;
    int wid = blockIdx.x * 4 + wv;
    int node = lane / 19;
    int k = lane - node * 19;
    int gn = wid * 3 + node;                 // global (b,n) index over B*N
    bool active = (node < 3) && (gn < BB * NN);
    int gnc = active ? gn : (BB * NN - 1);
    int n = gnc & (NN - 1);

    int d = n >> 10, h = (n >> 5) & 31, w = n & 31;
    int nd = d + OFF[k][0], nh = h + OFF[k][1], nw = w + OFF[k][2];
    bool valid = ((unsigned)nd < 32u) && ((unsigned)nh < 32u) && ((unsigned)nw < 32u);
    int nn = valid ? ((nd << 10) + (nh << 5) + nw) : n;

    const float* tr = theta + (size_t)gnc * 64;
    const float* pr = phi + (size_t)(gnc - n + nn) * 64;
    float acc = 0.f;
#pragma unroll
    for (int i = 0; i < 16; ++i) {
        float4 t = *(const float4*)(tr + i * 4);
        float4 p = *(const float4*)(pr + i * 4);
        acc = fmaf(t.x, p.x, acc); acc = fmaf(t.y, p.y, acc);
        acc = fmaf(t.z, p.z, acc); acc = fmaf(t.w, p.w, acc);
    }
    const float rs = 0.2294157338705618f;  // 1/sqrt(19)
    float s = fmaf(acc, rs, gsc[(size_t)n * KK + k]);

    if (active) sbuf[wv][node][k] = s;
    __syncthreads();
    float m = -INFINITY;
#pragma unroll
    for (int j = 0; j < KK; ++j) m = fmaxf(m, sbuf[wv][node][j]);
    float e = (active && valid) ? __expf(s - m) : 0.f;
    if (active) ebuf[wv][node][k] = e;
    __syncthreads();
    float sum = 0.f;
#pragma unroll
    for (int j = 0; j < KK; ++j) sum += ebuf[wv][node][j];
    if (active) wgt[((size_t)(gnc >> 15) * KK + k) * NN + n] = e / sum;
}

// ---------------- Kernel 4: one propagation iteration ----------------
__global__ __launch_bounds__(256) void prop_kernel(
    const float* __restrict__ cin, const float* __restrict__ wgt,
    float* __restrict__ cout)
{
    int gid = blockIdx.x * 256 + threadIdx.x;   // B*CC*N threads
    int n = gid & (NN - 1);
    int bc = gid >> 15;
    int b = bc / CC, c = bc % CC;
    int d = n >> 10, h = (n >> 5) & 31, w = n & 31;
    float acc = 0.f;
    const float* wb = wgt + (size_t)b * KK * NN;
    const float* cb = cin + ((size_t)b * CC + c) * NN;
#pragma unroll
    for (int k = 0; k < KK; ++k) {
        int nd = d + OFF[k][0], nh = h + OFF[k][1], nw = w + OFF[k][2];
        nd = min(max(nd, 0), 31); nh = min(max(nh, 0), 31); nw = min(max(nw, 0), 31);
        int nn = (nd << 10) + (nh << 5) + nw;
        acc += wb[(size_t)k * NN + n] * cb[nn];
    }
    cout[((size_t)b * CC + c) * NN + n] = acc;
}

extern "C" void kernel_launch(void* const* d_in, const int* in_sizes, int n_in,
                              void* d_out, int out_size, void* d_ws, size_t ws_size,
                              hipStream_t stream) {
    const float* cam = (const float*)d_in[0];
    const float* f   = (const float*)d_in[1];
    const float* thw = (const float*)d_in[2];
    const float* thb = (const float*)d_in[3];
    const float* phw = (const float*)d_in[4];
    const float* phb = (const float*)d_in[5];
    const float* gtw = (const float*)d_in[6];
    const float* gtb = (const float*)d_in[7];
    const float* gpw = (const float*)d_in[8];
    const float* gpb = (const float*)d_in[9];

    float* ws    = (float*)d_ws;
    float* theta = ws;                                   // [B,N,64]
    float* phi   = theta + (size_t)BB * NN * 64;         // [B,N,64]
    float* gth   = phi   + (size_t)BB * NN * 64;         // [N,64]
    float* gph   = gth   + (size_t)NN * 64;              // [N,64]
    float* wgt   = gph   + (size_t)NN * 64;              // [B,19,N]
    float* cam1  = wgt   + (size_t)BB * KK * NN;         // [B,21,N]
    float* gsc   = cam1;                                 // [N,19] aliases cam1:
    // gsc written by geo_score, read only by score_kernel; cam1 written by
    // prop_kernel strictly after score_kernel on the same stream.

    proj_kernel<<<1024, 256, 0, stream>>>(f, thw, thb, phw, phb, theta, phi);
    geo_kernel<<<NN / 4, 256, 0, stream>>>(gtw, gtb, gpw, gpb, gth, gph);
    {
        int waves = (NN + 2) / 3;
        int blocks = (waves + 3) / 4;
        geo_score_kernel<<<blocks, 256, 0, stream>>>(gth, gph, gsc);
    }
    {
        int waves = (BB * NN + 2) / 3;
        int blocks = (waves + 3) / 4;
        score_kernel<<<blocks, 256, 0, stream>>>(theta, phi, gsc, wgt);
    }
    prop_kernel<<<BB * CC * NN / 256, 256, 0, stream>>>(cam, wgt, cam1);
    prop_kernel<<<BB * CC * NN / 256, 256, 0, stream>>>(cam1, wgt, (float*)d_out);
}

// Round 4
// 152.266 us; speedup vs baseline: 1.2473x; 1.2473x over previous
//
#include <hip/hip_runtime.h>
#include <hip/hip_bf16.h>

#define DD 32
#define HH 32
#define WW 32
#define NN 32768
#define BB 2
#define CF 256
#define CC 21
#define FD 64
#define KK 19

typedef __attribute__((ext_vector_type(8))) short bf16x8;
typedef __attribute__((ext_vector_type(4))) float f32x4;

// 19 stencil offsets with |dx|+|dy|+|dz| <= 2 (order irrelevant: softmax+sum over k)
__device__ const int OFF[19][3] = {
    {-1,-1, 0}, {-1, 0,-1}, {-1, 0, 0}, {-1, 0, 1}, {-1, 1, 0},
    { 0,-1,-1}, { 0,-1, 0}, { 0,-1, 1}, { 0, 0,-1}, { 0, 0, 0},
    { 0, 0, 1}, { 0, 1,-1}, { 0, 1, 0}, { 0, 1, 1},
    { 1,-1, 0}, { 1, 0,-1}, { 1, 0, 0}, { 1, 0, 1}, { 1, 1, 0}
};

__device__ __forceinline__ unsigned short f2bf(float x) {
    unsigned u = __float_as_uint(x);
    u += 0x7FFFu + ((u >> 16) & 1u);       // round-to-nearest-even
    return (unsigned short)(u >> 16);
}
__device__ __forceinline__ float bf2f(unsigned short h) {
    return __uint_as_float((unsigned)h << 16);
}
#define QF(x) (((x) & 3) ^ (((x) >> 2) & 3))   // bank-spread slot xor

// ---------------- Kernel 0: weight prepack (f32 -> bf16 hi/lo fragments) ----
// frag (ks,kb,col): 8 shorts = bf16 of Wcat[ks*32+kb*8+e][col]; layout [ks][kb][col]
__global__ __launch_bounds__(256) void wprep_kernel(
    const float* __restrict__ thw, const float* __restrict__ phw,
    uint4* __restrict__ whi, uint4* __restrict__ wlo)
{
    int gid = blockIdx.x * 256 + threadIdx.x;   // 4096 fragments
    int col = gid & 127;
    int kb = (gid >> 7) & 3;
    int ks = gid >> 9;                          // 0..7
    const float* src = (col < 64) ? (thw + col) : (phw + (col - 64));
    int kbase = ks * 32 + kb * 8;
    unsigned hi4[4], lo4[4];
#pragma unroll
    for (int e2 = 0; e2 < 4; ++e2) {
        float va = src[(kbase + 2 * e2) * 64];
        float vb = src[(kbase + 2 * e2 + 1) * 64];
        unsigned short ha = f2bf(va), hb = f2bf(vb);
        unsigned short la = f2bf(va - bf2f(ha)), lb = f2bf(vb - bf2f(hb));
        hi4[e2] = (unsigned)ha | ((unsigned)hb << 16);
        lo4[e2] = (unsigned)la | ((unsigned)lb << 16);
    }
    int idx = (ks * 4 + kb) * 128 + col;
    whi[idx] = make_uint4(hi4[0], hi4[1], hi4[2], hi4[3]);
    wlo[idx] = make_uint4(lo4[0], lo4[1], lo4[2], lo4[3]);
}

// ---------------- Kernel 1: projection GEMM via split-bf16 MFMA ----------------
// C[b,n,j] = sum_c f[b,c,n]*Wcat[c,j] + bias; 128x128 tile, 4 waves, BK=32.
// acc += Ahi*Bhi + Alo*Bhi + Ahi*Blo  (~f32 accuracy at bf16 MFMA rate).
__global__ __launch_bounds__(256) void proj_kernel(
    const float* __restrict__ f,
    const uint4* __restrict__ whi, const uint4* __restrict__ wlo,
    const float* __restrict__ thb, const float* __restrict__ phb,
    float* __restrict__ theta, float* __restrict__ phi)
{
    __shared__ __align__(16) unsigned short Ahi[128][4][8];   // 8 KB each
    __shared__ __align__(16) unsigned short Alo[128][4][8];
    __shared__ __align__(16) unsigned short Bhi[128][4][8];
    __shared__ __align__(16) unsigned short Blo[128][4][8];

    int tid = threadIdx.x;
    int b = blockIdx.x >> 8;                  // 256 tiles per batch
    int n0 = (blockIdx.x & 255) * 128;
    int wv = tid >> 6, lane = tid & 63;
    int wr = (wv >> 1) * 64, wc = (wv & 1) * 64;
    int fr = lane & 15, kb_r = lane >> 4;

    int srow = tid & 127;                     // staging row (A) / col (B)
    int kb0 = (tid >> 7) * 2;                 // staging kb base: 0 or 2

    const float* fb = f + (size_t)b * CF * NN + n0;

    f32x4 acc[4][4];
#pragma unroll
    for (int mi = 0; mi < 4; ++mi)
#pragma unroll
        for (int ni = 0; ni < 4; ++ni) acc[mi][ni] = (f32x4){0.f, 0.f, 0.f, 0.f};

#pragma unroll 1
    for (int k0 = 0; k0 < CF; k0 += 32) {
        // ---- stage A: rows n0..n0+127, k = k0..k0+31; convert to hi/lo bf16
#pragma unroll
        for (int i = 0; i < 2; ++i) {
            int kb = kb0 + i;
            const float* src = fb + (size_t)(k0 + kb * 8) * NN + srow;
            unsigned hi4[4], lo4[4];
#pragma unroll
            for (int e2 = 0; e2 < 4; ++e2) {
                float va = src[(size_t)(2 * e2) * NN];
                float vb = src[(size_t)(2 * e2 + 1) * NN];
                unsigned short ha = f2bf(va), hb = f2bf(vb);
                unsigned short la = f2bf(va - bf2f(ha)), lb = f2bf(vb - bf2f(hb));
                hi4[e2] = (unsigned)ha | ((unsigned)hb << 16);
                lo4[e2] = (unsigned)la | ((unsigned)lb << 16);
            }
            int slot = kb ^ QF(srow);
            *(uint4*)&Ahi[srow][slot][0] = make_uint4(hi4[0], hi4[1], hi4[2], hi4[3]);
            *(uint4*)&Alo[srow][slot][0] = make_uint4(lo4[0], lo4[1], lo4[2], lo4[3]);
        }
        // ---- stage B: prepacked fragments, straight 16B copies
        {
            const uint4* wh = whi + (size_t)(k0 >> 5) * 4 * 128;
            const uint4* wl = wlo + (size_t)(k0 >> 5) * 4 * 128;
#pragma unroll
            for (int i = 0; i < 2; ++i) {
                int kb = kb0 + i;
                uint4 h = wh[kb * 128 + srow];
                uint4 l = wl[kb * 128 + srow];
                int slot = kb ^ QF(srow);
                *(uint4*)&Bhi[srow][slot][0] = h;
                *(uint4*)&Blo[srow][slot][0] = l;
            }
        }
        __syncthreads();
        // ---- fragments + MFMA
        bf16x8 ah[4], al[4], bh[4], bl[4];
#pragma unroll
        for (int mi = 0; mi < 4; ++mi) {
            int r = wr + mi * 16 + fr;
            int slot = kb_r ^ QF(r);
            ah[mi] = *(const bf16x8*)&Ahi[r][slot][0];
            al[mi] = *(const bf16x8*)&Alo[r][slot][0];
        }
#pragma unroll
        for (int ni = 0; ni < 4; ++ni) {
            int c = wc + ni * 16 + fr;
            int slot = kb_r ^ QF(c);
            bh[ni] = *(const bf16x8*)&Bhi[c][slot][0];
            bl[ni] = *(const bf16x8*)&Blo[c][slot][0];
        }
#pragma unroll
        for (int mi = 0; mi < 4; ++mi)
#pragma unroll
            for (int ni = 0; ni < 4; ++ni) {
                acc[mi][ni] = __builtin_amdgcn_mfma_f32_16x16x32_bf16(ah[mi], bh[ni], acc[mi][ni], 0, 0, 0);
                acc[mi][ni] = __builtin_amdgcn_mfma_f32_16x16x32_bf16(al[mi], bh[ni], acc[mi][ni], 0, 0, 0);
                acc[mi][ni] = __builtin_amdgcn_mfma_f32_16x16x32_bf16(ah[mi], bl[ni], acc[mi][ni], 0, 0, 0);
            }
        __syncthreads();
    }

    // ---- epilogue: C/D col=lane&15, row=(lane>>4)*4+r
#pragma unroll
    for (int ni = 0; ni < 4; ++ni) {
        int j = wc + ni * 16 + fr;
        float bj = (j < 64) ? thb[j] : phb[j - 64];
        float* outp = (j < 64) ? (theta + (size_t)b * NN * 64 + j)
                               : (phi + (size_t)b * NN * 64 + (j - 64));
#pragma unroll
        for (int mi = 0; mi < 4; ++mi) {
            int nbase = n0 + wr + mi * 16 + kb_r * 4;
#pragma unroll
            for (int r = 0; r < 4; ++r)
                outp[(size_t)(nbase + r) * 64] = acc[mi][ni][r] + bj;
        }
    }
}

// ---------------- Kernel 2: geo projection ----------------
__global__ __launch_bounds__(256) void geo_kernel(
    const float* __restrict__ gtw, const float* __restrict__ gtb,
    const float* __restrict__ gpw, const float* __restrict__ gpb,
    float* __restrict__ gth, float* __restrict__ gph)
{
    __shared__ float pe_s[4][48];
    int tid = threadIdx.x;
    int n_base = blockIdx.x * 4;
    if (tid < 192) {
        int node = tid / 48, p = tid % 48;
        int n = n_base + node;
        int d = n >> 10, h = (n >> 5) & 31, w = n & 31;
        int a = p / 16, rem = p % 16, i = rem >> 1, sc = rem & 1;
        float coord = (a == 0) ? (float)d : (a == 1) ? (float)h : (float)w;
        float div = expf(-9.210340371976184f * (float)i * 0.125f);  // (1e-4)^(i/8)
        float ang = coord * div;
        pe_s[node][p] = sc ? cosf(ang) : sinf(ang);
    }
    __syncthreads();
    int node = tid >> 6, j = tid & 63;
    int n = n_base + node;
    float at = gtb[j], ap = gpb[j];
#pragma unroll
    for (int p = 0; p < 48; ++p) {
        float pv = pe_s[node][p];
        at += pv * gtw[p * 64 + j];
        ap += pv * gpw[p * 64 + j];
    }
    gth[(size_t)n * 64 + j] = at;
    gph[(size_t)n * 64 + j] = ap;
}

// ---------------- Kernel 2b: geo scores (batch-independent) ----------------
__global__ __launch_bounds__(256) void geo_score_kernel(
    const float* __restrict__ gth, const float* __restrict__ gph,
    float* __restrict__ gsc)
{
    int wid = blockIdx.x * 4 + (threadIdx.x >> 6);
    int lane = threadIdx.x & 63;
    int node = lane / 19;
    int k = lane - node * 19;
    int n = wid * 3 + node;
    bool active = (node < 3) && (n < NN);
    if (!active) return;

    int d = n >> 10, h = (n >> 5) & 31, w = n & 31;
    int nd = d + OFF[k][0], nh = h + OFF[k][1], nw = w + OFF[k][2];
    bool valid = ((unsigned)nd < 32u) && ((unsigned)nh < 32u) && ((unsigned)nw < 32u);
    int nn = valid ? ((nd << 10) + (nh << 5) + nw) : n;

    const float* tr = gth + (size_t)n * 64;
    const float* pr = gph + (size_t)nn * 64;
    float acc = 0.f;
#pragma unroll
    for (int i = 0; i < 16; ++i) {
        float4 t = *(const float4*)(tr + i * 4);
        float4 p = *(const float4*)(pr + i * 4);
        acc = fmaf(t.x, p.x, acc); acc = fmaf(t.y, p.y, acc);
        acc = fmaf(t.z, p.z, acc); acc = fmaf(t.w, p.w, acc);
    }
    const float rs = 0.2294157338705618f;  // 1/sqrt(19)
    gsc[(size_t)n * KK + k] = valid ? acc * rs : -INFINITY;
}

// ---------------- Kernel 3: scores + masked softmax ----------------
__global__ __launch_bounds__(256) void score_kernel(
    const float* __restrict__ theta, const float* __restrict__ phi,
    const float* __restrict__ gsc, float* __restrict__ wgt)
{
    __shared__ float sbuf[4][3][20];
    __shared__ float ebuf[4][3][20];
    int wv = threadIdx.x >> 6;
    int lane = threadIdx.x & 63;
    int wid = blockIdx.x * 4 + wv;
    int node = lane / 19;
    int k = lane - node * 19;
    int gn = wid * 3 + node;                 // global (b,n) index over B*N
    bool active = (node < 3) && (gn < BB * NN);
    int gnc = active ? gn : (BB * NN - 1);
    int n = gnc & (NN - 1);

    int d = n >> 10, h = (n >> 5) & 31, w = n & 31;
    int nd = d + OFF[k][0], nh = h + OFF[k][1], nw = w + OFF[k][2];
    bool valid = ((unsigned)nd < 32u) && ((unsigned)nh < 32u) && ((unsigned)nw < 32u);
    int nn = valid ? ((nd << 10) + (nh << 5) + nw) : n;

    const float* tr = theta + (size_t)gnc * 64;
    const float* pr = phi + (size_t)(gnc - n + nn) * 64;
    float acc = 0.f;
#pragma unroll
    for (int i = 0; i < 16; ++i) {
        float4 t = *(const float4*)(tr + i * 4);
        float4 p = *(const float4*)(pr + i * 4);
        acc = fmaf(t.x, p.x, acc); acc = fmaf(t.y, p.y, acc);
        acc = fmaf(t.z, p.z, acc); acc = fmaf(t.w, p.w, acc);
    }
    const float rs = 0.2294157338705618f;  // 1/sqrt(19)
    float s = fmaf(acc, rs, gsc[(size_t)n * KK + k]);

    if (active) sbuf[wv][node][k] = s;
    __syncthreads();
    float m = -INFINITY;
#pragma unroll
    for (int j = 0; j < KK; ++j) m = fmaxf(m, sbuf[wv][node][j]);
    float e = (active && valid) ? __expf(s - m) : 0.f;
    if (active) ebuf[wv][node][k] = e;
    __syncthreads();
    float sum = 0.f;
#pragma unroll
    for (int j = 0; j < KK; ++j) sum += ebuf[wv][node][j];
    if (active) wgt[((size_t)(gnc >> 15) * KK + k) * NN + n] = e / sum;
}

// ---------------- Kernel 4: one propagation iteration ----------------
__global__ __launch_bounds__(256) void prop_kernel(
    const float* __restrict__ cin, const float* __restrict__ wgt,
    float* __restrict__ cout)
{
    int gid = blockIdx.x * 256 + threadIdx.x;   // B*CC*N threads
    int n = gid & (NN - 1);
    int bc = gid >> 15;
    int b = bc / CC, c = bc % CC;
    int d = n >> 10, h = (n >> 5) & 31, w = n & 31;
    float acc = 0.f;
    const float* wb = wgt + (size_t)b * KK * NN;
    const float* cb = cin + ((size_t)b * CC + c) * NN;
#pragma unroll
    for (int k = 0; k < KK; ++k) {
        int nd = d + OFF[k][0], nh = h + OFF[k][1], nw = w + OFF[k][2];
        nd = min(max(nd, 0), 31); nh = min(max(nh, 0), 31); nw = min(max(nw, 0), 31);
        int nn = (nd << 10) + (nh << 5) + nw;
        acc += wb[(size_t)k * NN + n] * cb[nn];
    }
    cout[((size_t)b * CC + c) * NN + n] = acc;
}

extern "C" void kernel_launch(void* const* d_in, const int* in_sizes, int n_in,
                              void* d_out, int out_size, void* d_ws, size_t ws_size,
                              hipStream_t stream) {
    const float* cam = (const float*)d_in[0];
    const float* f   = (const float*)d_in[1];
    const float* thw = (const float*)d_in[2];
    const float* thb = (const float*)d_in[3];
    const float* phw = (const float*)d_in[4];
    const float* phb = (const float*)d_in[5];
    const float* gtw = (const float*)d_in[6];
    const float* gtb = (const float*)d_in[7];
    const float* gpw = (const float*)d_in[8];
    const float* gpb = (const float*)d_in[9];

    float* ws    = (float*)d_ws;
    float* theta = ws;                                   // [B,N,64]
    float* phi   = theta + (size_t)BB * NN * 64;         // [B,N,64]
    float* gth   = phi   + (size_t)BB * NN * 64;         // [N,64]
    float* gph   = gth   + (size_t)NN * 64;              // [N,64]
    float* wgt   = gph   + (size_t)NN * 64;              // [B,19,N]
    float* cam1  = wgt   + (size_t)BB * KK * NN;         // [B,21,N] (1376256 floats)
    // Aliases inside the cam1 region (cam1 written only by prop, after all
    // readers of these are done):
    float* gsc   = cam1;                                 // [N,19] = 622592 floats
    uint4* whi   = (uint4*)(cam1 + 622592);              // 4096 uint4 = 16384 floats
    uint4* wlo   = whi + 4096;                           // 4096 uint4
    // total alias use: 622592 + 32768 = 655360 < 1376256 floats. Order:
    // wprep(writes whi/wlo) -> proj(reads) -> geo_score(writes gsc, disjoint)
    // -> score(reads gsc) -> prop(overwrites cam1).

    wprep_kernel<<<16, 256, 0, stream>>>(thw, phw, whi, wlo);
    proj_kernel<<<512, 256, 0, stream>>>(f, whi, wlo, thb, phb, theta, phi);
    geo_kernel<<<NN / 4, 256, 0, stream>>>(gtw, gtb, gpw, gpb, gth, gph);
    {
        int waves = (NN + 2) / 3;
        int blocks = (waves + 3) / 4;
        geo_score_kernel<<<blocks, 256, 0, stream>>>(gth, gph, gsc);
    }
    {
        int waves = (BB * NN + 2) / 3;
        int blocks = (waves + 3) / 4;
        score_kernel<<<blocks, 256, 0, stream>>>(theta, phi, gsc, wgt);
    }
    prop_kernel<<<BB * CC * NN / 256, 256, 0, stream>>>(cam, wgt, cam1);
    prop_kernel<<<BB * CC * NN / 256, 256, 0, stream>>>(cam1, wgt, (float*)d_out);
}

// Round 5
// 106.516 us; speedup vs baseline: 1.7830x; 1.4295x over previous
//
#include <hip/hip_runtime.h>
#include <hip/hip_bf16.h>

#define DD 32
#define HH 32
#define WW 32
#define NN 32768
#define BB 2
#define CF 256
#define CC 21
#define FD 64
#define KK 19

typedef __attribute__((ext_vector_type(8))) short bf16x8;
typedef __attribute__((ext_vector_type(4))) float f32x4;

// 19 stencil offsets with |dx|+|dy|+|dz| <= 2 (order irrelevant: softmax+sum over k)
__device__ const int OFF[19][3] = {
    {-1,-1, 0}, {-1, 0,-1}, {-1, 0, 0}, {-1, 0, 1}, {-1, 1, 0},
    { 0,-1,-1}, { 0,-1, 0}, { 0,-1, 1}, { 0, 0,-1}, { 0, 0, 0},
    { 0, 0, 1}, { 0, 1,-1}, { 0, 1, 0}, { 0, 1, 1},
    { 1,-1, 0}, { 1, 0,-1}, { 1, 0, 0}, { 1, 0, 1}, { 1, 1, 0}
};

__device__ __forceinline__ unsigned short f2bf(float x) {
    unsigned u = __float_as_uint(x);
    u += 0x7FFFu + ((u >> 16) & 1u);       // round-to-nearest-even
    return (unsigned short)(u >> 16);
}
__device__ __forceinline__ float bf2f(unsigned short h) {
    return __uint_as_float((unsigned)h << 16);
}
#define QF(x) (((x) & 3) ^ (((x) >> 2) & 3))   // bank-spread slot xor

// ---------------- Kernel 0: weight prepack (f32 -> bf16 hi/lo fragments) ----
__global__ __launch_bounds__(256) void wprep_kernel(
    const float* __restrict__ thw, const float* __restrict__ phw,
    uint4* __restrict__ whi, uint4* __restrict__ wlo)
{
    int gid = blockIdx.x * 256 + threadIdx.x;   // 4096 fragments
    int col = gid & 127;
    int kb = (gid >> 7) & 3;
    int ks = gid >> 9;                          // 0..7
    const float* src = (col < 64) ? (thw + col) : (phw + (col - 64));
    int kbase = ks * 32 + kb * 8;
    unsigned hi4[4], lo4[4];
#pragma unroll
    for (int e2 = 0; e2 < 4; ++e2) {
        float va = src[(kbase + 2 * e2) * 64];
        float vb = src[(kbase + 2 * e2 + 1) * 64];
        unsigned short ha = f2bf(va), hb = f2bf(vb);
        unsigned short la = f2bf(va - bf2f(ha)), lb = f2bf(vb - bf2f(hb));
        hi4[e2] = (unsigned)ha | ((unsigned)hb << 16);
        lo4[e2] = (unsigned)la | ((unsigned)lb << 16);
    }
    int idx = (ks * 4 + kb) * 128 + col;
    whi[idx] = make_uint4(hi4[0], hi4[1], hi4[2], hi4[3]);
    wlo[idx] = make_uint4(lo4[0], lo4[1], lo4[2], lo4[3]);
}

// ---------------- Kernel 1: projection GEMM via split-bf16 MFMA ----------------
__global__ __launch_bounds__(256) void proj_kernel(
    const float* __restrict__ f,
    const uint4* __restrict__ whi, const uint4* __restrict__ wlo,
    const float* __restrict__ thb, const float* __restrict__ phb,
    float* __restrict__ theta, float* __restrict__ phi)
{
    __shared__ __align__(16) unsigned short Ahi[128][4][8];   // 8 KB each
    __shared__ __align__(16) unsigned short Alo[128][4][8];
    __shared__ __align__(16) unsigned short Bhi[128][4][8];
    __shared__ __align__(16) unsigned short Blo[128][4][8];

    int tid = threadIdx.x;
    int b = blockIdx.x >> 8;                  // 256 tiles per batch
    int n0 = (blockIdx.x & 255) * 128;
    int wv = tid >> 6, lane = tid & 63;
    int wr = (wv >> 1) * 64, wc = (wv & 1) * 64;
    int fr = lane & 15, kb_r = lane >> 4;

    int srow = tid & 127;                     // staging row (A) / col (B)
    int kb0 = (tid >> 7) * 2;                 // staging kb base: 0 or 2

    const float* fb = f + (size_t)b * CF * NN + n0;

    f32x4 acc[4][4];
#pragma unroll
    for (int mi = 0; mi < 4; ++mi)
#pragma unroll
        for (int ni = 0; ni < 4; ++ni) acc[mi][ni] = (f32x4){0.f, 0.f, 0.f, 0.f};

#pragma unroll 1
    for (int k0 = 0; k0 < CF; k0 += 32) {
#pragma unroll
        for (int i = 0; i < 2; ++i) {
            int kb = kb0 + i;
            const float* src = fb + (size_t)(k0 + kb * 8) * NN + srow;
            unsigned hi4[4], lo4[4];
#pragma unroll
            for (int e2 = 0; e2 < 4; ++e2) {
                float va = src[(size_t)(2 * e2) * NN];
                float vb = src[(size_t)(2 * e2 + 1) * NN];
                unsigned short ha = f2bf(va), hb = f2bf(vb);
                unsigned short la = f2bf(va - bf2f(ha)), lb = f2bf(vb - bf2f(hb));
                hi4[e2] = (unsigned)ha | ((unsigned)hb << 16);
                lo4[e2] = (unsigned)la | ((unsigned)lb << 16);
            }
            int slot = kb ^ QF(srow);
            *(uint4*)&Ahi[srow][slot][0] = make_uint4(hi4[0], hi4[1], hi4[2], hi4[3]);
            *(uint4*)&Alo[srow][slot][0] = make_uint4(lo4[0], lo4[1], lo4[2], lo4[3]);
        }
        {
            const uint4* wh = whi + (size_t)(k0 >> 5) * 4 * 128;
            const uint4* wl = wlo + (size_t)(k0 >> 5) * 4 * 128;
#pragma unroll
            for (int i = 0; i < 2; ++i) {
                int kb = kb0 + i;
                uint4 hh = wh[kb * 128 + srow];
                uint4 ll = wl[kb * 128 + srow];
                int slot = kb ^ QF(srow);
                *(uint4*)&Bhi[srow][slot][0] = hh;
                *(uint4*)&Blo[srow][slot][0] = ll;
            }
        }
        __syncthreads();
        bf16x8 ah[4], al[4], bh[4], bl[4];
#pragma unroll
        for (int mi = 0; mi < 4; ++mi) {
            int r = wr + mi * 16 + fr;
            int slot = kb_r ^ QF(r);
            ah[mi] = *(const bf16x8*)&Ahi[r][slot][0];
            al[mi] = *(const bf16x8*)&Alo[r][slot][0];
        }
#pragma unroll
        for (int ni = 0; ni < 4; ++ni) {
            int c = wc + ni * 16 + fr;
            int slot = kb_r ^ QF(c);
            bh[ni] = *(const bf16x8*)&Bhi[c][slot][0];
            bl[ni] = *(const bf16x8*)&Blo[c][slot][0];
        }
#pragma unroll
        for (int mi = 0; mi < 4; ++mi)
#pragma unroll
            for (int ni = 0; ni < 4; ++ni) {
                acc[mi][ni] = __builtin_amdgcn_mfma_f32_16x16x32_bf16(ah[mi], bh[ni], acc[mi][ni], 0, 0, 0);
                acc[mi][ni] = __builtin_amdgcn_mfma_f32_16x16x32_bf16(al[mi], bh[ni], acc[mi][ni], 0, 0, 0);
                acc[mi][ni] = __builtin_amdgcn_mfma_f32_16x16x32_bf16(ah[mi], bl[ni], acc[mi][ni], 0, 0, 0);
            }
        __syncthreads();
    }

#pragma unroll
    for (int ni = 0; ni < 4; ++ni) {
        int j = wc + ni * 16 + fr;
        float bj = (j < 64) ? thb[j] : phb[j - 64];
        float* outp = (j < 64) ? (theta + (size_t)b * NN * 64 + j)
                               : (phi + (size_t)b * NN * 64 + (j - 64));
#pragma unroll
        for (int mi = 0; mi < 4; ++mi) {
            int nbase = n0 + wr + mi * 16 + kb_r * 4;
#pragma unroll
            for (int r = 0; r < 4; ++r)
                outp[(size_t)(nbase + r) * 64] = acc[mi][ni][r] + bj;
        }
    }
}

// ---------------- Kernel 2: geo projection ----------------
__global__ __launch_bounds__(256) void geo_kernel(
    const float* __restrict__ gtw, const float* __restrict__ gtb,
    const float* __restrict__ gpw, const float* __restrict__ gpb,
    float* __restrict__ gth, float* __restrict__ gph)
{
    __shared__ float pe_s[4][48];
    int tid = threadIdx.x;
    int n_base = blockIdx.x * 4;
    if (tid < 192) {
        int node = tid / 48, p = tid % 48;
        int n = n_base + node;
        int d = n >> 10, h = (n >> 5) & 31, w = n & 31;
        int a = p / 16, rem = p % 16, i = rem >> 1, sc = rem & 1;
        float coord = (a == 0) ? (float)d : (a == 1) ? (float)h : (float)w;
        float div = expf(-9.210340371976184f * (float)i * 0.125f);  // (1e-4)^(i/8)
        float ang = coord * div;
        pe_s[node][p] = sc ? cosf(ang) : sinf(ang);
    }
    __syncthreads();
    int node = tid >> 6, j = tid & 63;
    int n = n_base + node;
    float at = gtb[j], ap = gpb[j];
#pragma unroll
    for (int p = 0; p < 48; ++p) {
        float pv = pe_s[node][p];
        at += pv * gtw[p * 64 + j];
        ap += pv * gpw[p * 64 + j];
    }
    gth[(size_t)n * 64 + j] = at;
    gph[(size_t)n * 64 + j] = ap;
}

// ---------------- Kernel 2b: geo scores (batch-independent) ----------------
// wave = 4 nodes x 16 column-lanes; coalesced 1KB row loads; shfl_xor reduce.
// gsc[n,k] = rs * (g_theta[n].g_phi[nbr]), -inf for invalid edges.
__global__ __launch_bounds__(256) void geo_score_kernel(
    const float* __restrict__ gth, const float* __restrict__ gph,
    float* __restrict__ gsc)
{
    int tid = threadIdx.x;
    int lane = tid & 63;
    int wv = tid >> 6;
    int sub = lane >> 4;
    int col4 = lane & 15;
    int n = blockIdx.x * 16 + wv * 4 + sub;
    int d = n >> 10, h = (n >> 5) & 31, w = n & 31;

    float4 tq = *(const float4*)(gth + (size_t)n * 64 + col4 * 4);
    const float rs = 0.2294157338705618f;  // 1/sqrt(19)

    float s[KK];
#pragma unroll
    for (int k = 0; k < KK; ++k) {
        int nd = d + OFF[k][0], nh = h + OFF[k][1], nw = w + OFF[k][2];
        bool valid = ((unsigned)nd < 32u) && ((unsigned)nh < 32u) && ((unsigned)nw < 32u);
        nd = min(max(nd, 0), 31); nh = min(max(nh, 0), 31); nw = min(max(nw, 0), 31);
        int nn = (nd << 10) + (nh << 5) + nw;
        float4 p = *(const float4*)(gph + (size_t)nn * 64 + col4 * 4);
        float part = tq.x * p.x + tq.y * p.y + tq.z * p.z + tq.w * p.w;
        part += __shfl_xor(part, 1, 16);
        part += __shfl_xor(part, 2, 16);
        part += __shfl_xor(part, 4, 16);
        part += __shfl_xor(part, 8, 16);
        s[k] = valid ? part * rs : -INFINITY;
    }
#pragma unroll
    for (int kk2 = 0; kk2 < 2; ++kk2) {
        int k = kk2 * 16 + col4;
        if (k < KK) gsc[(size_t)n * KK + k] = s[k];
    }
}

// ---------------- Kernel 3: scores + masked softmax ----------------
// wave = 4 nodes x 16 column-lanes; per k one coalesced phi-row load + 4-step
// shfl_xor(16) reduce -> all 16 lanes hold s_k; softmax done in-register.
__global__ __launch_bounds__(256) void score_kernel(
    const float* __restrict__ theta, const float* __restrict__ phi,
    const float* __restrict__ gsc, float* __restrict__ wgt)
{
    int tid = threadIdx.x;
    int lane = tid & 63;
    int wv = tid >> 6;
    int sub = lane >> 4;
    int col4 = lane & 15;
    int gn = blockIdx.x * 16 + wv * 4 + sub;    // over B*N
    int b = gn >> 15;
    int n = gn & (NN - 1);
    int d = n >> 10, h = (n >> 5) & 31, w = n & 31;

    float4 tq = *(const float4*)(theta + (size_t)gn * 64 + col4 * 4);
    const float* pb = phi + (size_t)b * NN * 64;
    const float* gr = gsc + (size_t)n * KK;
    const float rs = 0.2294157338705618f;  // 1/sqrt(19)

    float s[KK];
#pragma unroll
    for (int k = 0; k < KK; ++k) {
        int nd = d + OFF[k][0], nh = h + OFF[k][1], nw = w + OFF[k][2];
        nd = min(max(nd, 0), 31); nh = min(max(nh, 0), 31); nw = min(max(nw, 0), 31);
        int nn = (nd << 10) + (nh << 5) + nw;
        float4 p = *(const float4*)(pb + (size_t)nn * 64 + col4 * 4);
        float part = tq.x * p.x + tq.y * p.y + tq.z * p.z + tq.w * p.w;
        part += __shfl_xor(part, 1, 16);
        part += __shfl_xor(part, 2, 16);
        part += __shfl_xor(part, 4, 16);
        part += __shfl_xor(part, 8, 16);
        // gsc carries rs*geo_dot, or -inf for invalid edges
        s[k] = fmaf(part, rs, gr[k]);
    }
    float m = s[0];
#pragma unroll
    for (int k = 1; k < KK; ++k) m = fmaxf(m, s[k]);
    float sum = 0.f;
#pragma unroll
    for (int k = 0; k < KK; ++k) { s[k] = __expf(s[k] - m); sum += s[k]; }
    float inv = 1.f / sum;
#pragma unroll
    for (int kk2 = 0; kk2 < 2; ++kk2) {
        int k = kk2 * 16 + col4;
        if (k < KK) wgt[((size_t)b * KK + k) * NN + n] = s[k] * inv;
    }
}

// ---------------- Kernel 4: one propagation iteration ----------------
__global__ __launch_bounds__(256) void prop_kernel(
    const float* __restrict__ cin, const float* __restrict__ wgt,
    float* __restrict__ cout)
{
    int gid = blockIdx.x * 256 + threadIdx.x;   // B*CC*N threads
    int n = gid & (NN - 1);
    int bc = gid >> 15;
    int b = bc / CC, c = bc % CC;
    int d = n >> 10, h = (n >> 5) & 31, w = n & 31;
    float acc = 0.f;
    const float* wb = wgt + (size_t)b * KK * NN;
    const float* cb = cin + ((size_t)b * CC + c) * NN;
#pragma unroll
    for (int k = 0; k < KK; ++k) {
        int nd = d + OFF[k][0], nh = h + OFF[k][1], nw = w + OFF[k][2];
        nd = min(max(nd, 0), 31); nh = min(max(nh, 0), 31); nw = min(max(nw, 0), 31);
        int nn = (nd << 10) + (nh << 5) + nw;
        acc += wb[(size_t)k * NN + n] * cb[nn];
    }
    cout[((size_t)b * CC + c) * NN + n] = acc;
}

extern "C" void kernel_launch(void* const* d_in, const int* in_sizes, int n_in,
                              void* d_out, int out_size, void* d_ws, size_t ws_size,
                              hipStream_t stream) {
    const float* cam = (const float*)d_in[0];
    const float* f   = (const float*)d_in[1];
    const float* thw = (const float*)d_in[2];
    const float* thb = (const float*)d_in[3];
    const float* phw = (const float*)d_in[4];
    const float* phb = (const float*)d_in[5];
    const float* gtw = (const float*)d_in[6];
    const float* gtb = (const float*)d_in[7];
    const float* gpw = (const float*)d_in[8];
    const float* gpb = (const float*)d_in[9];

    float* ws    = (float*)d_ws;
    float* theta = ws;                                   // [B,N,64]
    float* phi   = theta + (size_t)BB * NN * 64;         // [B,N,64]
    float* gth   = phi   + (size_t)BB * NN * 64;         // [N,64]
    float* gph   = gth   + (size_t)NN * 64;              // [N,64]
    float* wgt   = gph   + (size_t)NN * 64;              // [B,19,N]
    float* cam1  = wgt   + (size_t)BB * KK * NN;         // [B,21,N] (1376256 floats)
    float* gsc   = cam1;                                 // [N,19] aliases cam1
    uint4* whi   = (uint4*)(cam1 + 622592);              // 4096 uint4
    uint4* wlo   = whi + 4096;                           // 4096 uint4
    // order: wprep(whi/wlo) -> proj(reads) -> geo_score(gsc) -> score(reads
    // gsc) -> prop(overwrites cam1). All within cam1 region, no overlap races.

    wprep_kernel<<<16, 256, 0, stream>>>(thw, phw, whi, wlo);
    proj_kernel<<<512, 256, 0, stream>>>(f, whi, wlo, thb, phb, theta, phi);
    geo_kernel<<<NN / 4, 256, 0, stream>>>(gtw, gtb, gpw, gpb, gth, gph);
    geo_score_kernel<<<NN / 16, 256, 0, stream>>>(gth, gph, gsc);
    score_kernel<<<BB * NN / 16, 256, 0, stream>>>(theta, phi, gsc, wgt);
    prop_kernel<<<BB * CC * NN / 256, 256, 0, stream>>>(cam, wgt, cam1);
    prop_kernel<<<BB * CC * NN / 256, 256, 0, stream>>>(cam1, wgt, (float*)d_out);
}